// Round 8
// baseline (294.042 us; speedup 1.0000x reference)
//
#include <hip/hip_runtime.h>
#include <math.h>

#define N_NODES 50000
#define E_EDGES 800000
#define F_IN 16
#define H_HEADS 8
#define HID 128
#define NEG_SLOPE 0.2f
#define N_PART 8
#define PART_SZ ((N_NODES + N_PART - 1) / N_PART)  // 6250

// f32 -> bf16 round-to-nearest-even
__device__ __forceinline__ unsigned short f2bf(float f) {
    unsigned u = __float_as_uint(f);
    return (unsigned short)((u + 0x7FFFu + ((u >> 16) & 1u)) >> 16);
}

// ========================= CSR build (real edges only; self-loops analytic) =========================

__global__ void zero_deg(int* __restrict__ deg) {
    int t = blockIdx.x * 256 + threadIdx.x;
    if (t < N_NODES) deg[t] = 0;
}

__global__ void hist_dst(const int* __restrict__ ei, int* __restrict__ deg) {
    int part = blockIdx.x & 7;
    int e = (blockIdx.x >> 3) * 256 + threadIdx.x;
    if (e >= E_EDGES) return;
    int d = ei[E_EDGES + e];
    if (d / PART_SZ == part) atomicAdd(&deg[d], 1);
}

__global__ void scan1(const int* __restrict__ deg, int* __restrict__ rowptr,
                      int* __restrict__ partial) {
    __shared__ int tmp[256];
    int tid = threadIdx.x;
    int t = blockIdx.x * 256 + tid;
    int v = (t < N_NODES) ? deg[t] : 0;
    tmp[tid] = v;
    __syncthreads();
    for (int off = 1; off < 256; off <<= 1) {
        int add = (tid >= off) ? tmp[tid - off] : 0;
        __syncthreads();
        tmp[tid] += add;
        __syncthreads();
    }
    if (t < N_NODES) rowptr[t] = tmp[tid] - v;
    if (tid == 255) partial[blockIdx.x] = tmp[255];
}

__global__ void scan2(int* __restrict__ partial, int nblk) {
    __shared__ int tmp[256];
    int tid = threadIdx.x;
    int v = (tid < nblk) ? partial[tid] : 0;
    tmp[tid] = v;
    __syncthreads();
    for (int off = 1; off < 256; off <<= 1) {
        int add = (tid >= off) ? tmp[tid - off] : 0;
        __syncthreads();
        tmp[tid] += add;
        __syncthreads();
    }
    if (tid < nblk) partial[tid] = tmp[tid] - v;
}

__global__ void scan3(int* __restrict__ rowptr, const int* __restrict__ partial,
                      int* __restrict__ deg) {
    int t = blockIdx.x * 256 + threadIdx.x;
    if (t < N_NODES) {
        rowptr[t] += partial[blockIdx.x];
        deg[t] = 0;
    }
    if (t == 0) rowptr[N_NODES] = E_EDGES;
}

__global__ void scatter(const int* __restrict__ ei, const int* __restrict__ rowptr,
                        int* __restrict__ cursor, int* __restrict__ csr) {
    int part = blockIdx.x & 7;
    int e = (blockIdx.x >> 3) * 256 + threadIdx.x;
    if (e >= E_EDGES) return;
    int d = ei[E_EDGES + e];
    if (d / PART_SZ != part) return;
    int s = ei[e];
    int pos = atomicAdd(&cursor[d], 1);
    csr[rowptr[d] + pos] = s;
}

// ========== tiled GEMM: A[M,K] @ W[K,128] -> bf16 C + fused per-head AL dots ==========
template <int K>
__global__ __launch_bounds__(256) void gemm_tile(const float* __restrict__ A,
                                                 const float* __restrict__ W,
                                                 unsigned short* __restrict__ C,
                                                 const float* __restrict__ a_src,
                                                 const float* __restrict__ a_dst,
                                                 float* __restrict__ alS,
                                                 float* __restrict__ alD, int M) {
    constexpr int BK = (K < 32) ? K : 32;
    constexpr int BKQ = BK / 4;
    __shared__ float sA[BK][128];  // transposed: sA[k][row]
    __shared__ float sW[BK][128];
    int tid = threadIdx.x;
    int tx = tid & 15, ty = tid >> 4;
    int row0 = blockIdx.x * 128;
    float acc[8][8] = {};

    for (int kc = 0; kc < K; kc += BK) {
#pragma unroll
        for (int f = tid; f < 128 * BKQ; f += 256) {
            int r = f / BKQ, kq = f % BKQ;
            int gr = row0 + r;
            float4 v = (gr < M) ? *(const float4*)(A + (size_t)gr * K + kc + kq * 4)
                                : make_float4(0.f, 0.f, 0.f, 0.f);
            sA[kq * 4 + 0][r] = v.x;
            sA[kq * 4 + 1][r] = v.y;
            sA[kq * 4 + 2][r] = v.z;
            sA[kq * 4 + 3][r] = v.w;
        }
#pragma unroll
        for (int f = tid; f < BK * 32; f += 256) {
            int kr = f / 32, cq = f % 32;
            *(float4*)(&sW[kr][cq * 4]) =
                *(const float4*)(W + (size_t)(kc + kr) * 128 + cq * 4);
        }
        __syncthreads();
#pragma unroll
        for (int k = 0; k < BK; k++) {
            float4 a0 = *(const float4*)(&sA[k][ty * 8]);
            float4 a1 = *(const float4*)(&sA[k][ty * 8 + 4]);
            float4 w0 = *(const float4*)(&sW[k][tx * 4]);
            float4 w1 = *(const float4*)(&sW[k][64 + tx * 4]);
            float av[8] = {a0.x, a0.y, a0.z, a0.w, a1.x, a1.y, a1.z, a1.w};
            float wv[8] = {w0.x, w0.y, w0.z, w0.w, w1.x, w1.y, w1.z, w1.w};
#pragma unroll
            for (int i = 0; i < 8; i++)
#pragma unroll
                for (int j = 0; j < 8; j++) acc[i][j] += av[i] * wv[j];
        }
        __syncthreads();
    }

    int hd0 = tx >> 2, co = (tx & 3) * 4;
    float4 as0 = *(const float4*)(a_src + hd0 * 16 + co);
    float4 as1 = *(const float4*)(a_src + (4 + hd0) * 16 + co);
    float4 ad0 = *(const float4*)(a_dst + hd0 * 16 + co);
    float4 ad1 = *(const float4*)(a_dst + (4 + hd0) * 16 + co);

#pragma unroll
    for (int i = 0; i < 8; i++) {
        int gr = row0 + ty * 8 + i;
        if (gr >= M) break;
        float4 c0 = make_float4(acc[i][0], acc[i][1], acc[i][2], acc[i][3]);
        float4 c1 = make_float4(acc[i][4], acc[i][5], acc[i][6], acc[i][7]);
        ushort4 p0 = {f2bf(c0.x), f2bf(c0.y), f2bf(c0.z), f2bf(c0.w)};
        ushort4 p1 = {f2bf(c1.x), f2bf(c1.y), f2bf(c1.z), f2bf(c1.w)};
        *(ushort4*)(C + (size_t)gr * 128 + tx * 4) = p0;
        *(ushort4*)(C + (size_t)gr * 128 + 64 + tx * 4) = p1;
        float s1a = c0.x * as0.x + c0.y * as0.y + c0.z * as0.z + c0.w * as0.w;
        float s1b = c1.x * as1.x + c1.y * as1.y + c1.z * as1.z + c1.w * as1.w;
        float s2a = c0.x * ad0.x + c0.y * ad0.y + c0.z * ad0.z + c0.w * ad0.w;
        float s2b = c1.x * ad1.x + c1.y * ad1.y + c1.z * ad1.z + c1.w * ad1.w;
        s1a += __shfl_xor(s1a, 1); s1a += __shfl_xor(s1a, 2);
        s1b += __shfl_xor(s1b, 1); s1b += __shfl_xor(s1b, 2);
        s2a += __shfl_xor(s2a, 1); s2a += __shfl_xor(s2a, 2);
        s2b += __shfl_xor(s2b, 1); s2b += __shfl_xor(s2b, 2);
        if ((tx & 3) == 0) {
            alS[gr * 8 + hd0] = s1a;
            alS[gr * 8 + 4 + hd0] = s1b;
            alD[gr * 8 + hd0] = s2a;
            alD[gr * 8 + 4 + hd0] = s2b;
        }
    }
}

// ============ per-node aggregation: p computed once per (edge,head) ============
// Main rounds of 8 edges: lane (e,h)=(lane>>3, lane&7) computes p_e,h (1 alS load +
// 1 exp per ROUND instead of per edge); channel lanes pull their p via __shfl.
// ssum assembled from p-space partials with a 3-step shfl_xor reduce at the end.
template <int MODE>
__global__ void node_agg(const int* __restrict__ rowptr, const int* __restrict__ csr,
                         const float* __restrict__ alS, const float* __restrict__ alD,
                         const unsigned short* __restrict__ hbf, const float* __restrict__ b,
                         float* __restrict__ h_out, const float* __restrict__ fcw,
                         const float* __restrict__ fcb, float* __restrict__ fco) {
    int node = blockIdx.x * 4 + (threadIdx.x >> 6);
    if (node >= N_NODES) return;
    int lane = threadIdx.x & 63;
    int row0 = __builtin_amdgcn_readfirstlane(rowptr[node]);
    int deg = __builtin_amdgcn_readfirstlane(rowptr[node + 1]) - row0;
    int h0 = lane >> 3;  // channel-head (lane owns channels 2*lane, 2*lane+1)
    int hp = lane & 7;   // p-compute head
    int ep = lane >> 3;  // p-compute edge slot
    float ald_c = alD[node * 8 + h0];
    float ald_p = alD[node * 8 + hp];

    // self-loop term (channel space; identical within each h0 group)
    float es = alS[node * 8 + h0] + ald_c;
    es = es > 0.f ? es : NEG_SLOPE * es;
    float ps = __expf(es);
    unsigned gsl = ((const unsigned*)(hbf + (size_t)node * HID))[lane];
    float ssc = ps;  // channel-space sum (self-loop + tail)
    float acc0 = ps * __uint_as_float(gsl << 16);
    float acc1 = ps * __uint_as_float(gsl & 0xFFFF0000u);
    float psum = 0.f;  // p-space partial sum (main rounds)

    int i = 0;
    for (; i + 8 <= deg; i += 8) {
        int su[8];
#pragma unroll
        for (int j = 0; j < 8; j++)
            su[j] = __builtin_amdgcn_readfirstlane(csr[row0 + i + j]);
        int se = csr[row0 + i + ep];       // per-lane edge for p compute
        float av = alS[se * 8 + hp];       // ONE alS gather per round per lane
        unsigned gg[8];
#pragma unroll
        for (int j = 0; j < 8; j++)
            gg[j] = ((const unsigned*)(hbf + (size_t)su[j] * HID))[lane];
        float e = av + ald_p;
        e = e > 0.f ? e : NEG_SLOPE * e;
        float pe = __expf(e);              // ONE exp per round per lane
        psum += pe;
#pragma unroll
        for (int j = 0; j < 8; j++) {
            float p = __shfl(pe, j * 8 + h0);
            acc0 += p * __uint_as_float(gg[j] << 16);
            acc1 += p * __uint_as_float(gg[j] & 0xFFFF0000u);
        }
    }
    // tail (<8 edges): old per-lane path in channel space
    for (; i < deg; i++) {
        int s0 = __builtin_amdgcn_readfirstlane(csr[row0 + i]);
        float a0 = alS[s0 * 8 + h0];
        unsigned g0 = ((const unsigned*)(hbf + (size_t)s0 * HID))[lane];
        float e0 = a0 + ald_c;
        e0 = e0 > 0.f ? e0 : NEG_SLOPE * e0;
        float p0 = __expf(e0);
        ssc += p0;
        acc0 += p0 * __uint_as_float(g0 << 16);
        acc1 += p0 * __uint_as_float(g0 & 0xFFFF0000u);
    }

    // fold p-space partials: sum over lanes sharing hp (bits 3..5), then fetch my h0
    float pr = psum;
    pr += __shfl_xor(pr, 8);
    pr += __shfl_xor(pr, 16);
    pr += __shfl_xor(pr, 32);
    float ssum = ssc + __shfl(pr, h0);  // lane h0 holds head-h0 total

    float2 bv = *(const float2*)(b + lane * 2);
    float inv = 1.f / ssum;
    float v0 = acc0 * inv + bv.x;
    float v1 = acc1 * inv + bv.y;
    v0 = v0 > 0.f ? v0 : (__expf(v0) - 1.f);
    v1 = v1 > 0.f ? v1 : (__expf(v1) - 1.f);
    if (MODE == 0) {
        *(float2*)(h_out + (size_t)node * HID + lane * 2) = make_float2(v0, v1);
    } else {
        float2 fw = *(const float2*)(fcw + lane * 2);
        float r = v0 * fw.x + v1 * fw.y;
#pragma unroll
        for (int off = 32; off; off >>= 1) r += __shfl_down(r, off);
        if (lane == 0) fco[node] = r + fcb[0];
    }
}

// ========================= launch =========================

extern "C" void kernel_launch(void* const* d_in, const int* in_sizes, int n_in,
                              void* d_out, int out_size, void* d_ws, size_t ws_size,
                              hipStream_t stream) {
    const float* x   = (const float*)d_in[0];
    const int*   ei  = (const int*)d_in[1];
    const float* W1  = (const float*)d_in[2];
    const float* a1s = (const float*)d_in[3];
    const float* a1d = (const float*)d_in[4];
    const float* b1  = (const float*)d_in[5];
    const float* W2  = (const float*)d_in[6];
    const float* a2s = (const float*)d_in[7];
    const float* a2d = (const float*)d_in[8];
    const float* b2  = (const float*)d_in[9];
    const float* W3  = (const float*)d_in[10];
    const float* a3s = (const float*)d_in[11];
    const float* a3d = (const float*)d_in[12];
    const float* b3  = (const float*)d_in[13];
    const float* fcw = (const float*)d_in[14];
    const float* fcb = (const float*)d_in[15];
    float* out = (float*)d_out;

    char* ws = (char*)d_ws;
    size_t off = 0;
    float* bufB = (float*)(ws + off);            off += (size_t)N_NODES * HID * 4;
    unsigned short* bufH = (unsigned short*)(ws + off); off += (size_t)N_NODES * HID * 2;
    float* alS  = (float*)(ws + off); off += (size_t)N_NODES * H_HEADS * 4;
    float* alD  = (float*)(ws + off); off += (size_t)N_NODES * H_HEADS * 4;
    int* deg    = (int*)(ws + off);   off += (size_t)N_NODES * 4;
    int* rowptr = (int*)(ws + off);   off += (size_t)(N_NODES + 1) * 4;
    int* partial= (int*)(ws + off);   off += 256 * 4;
    int* csr    = (int*)(ws + off);   off += (size_t)E_EDGES * 4;

    const int NB_N  = (N_NODES + 255) / 256;
    const int NB_E8 = ((E_EDGES + 255) / 256) * N_PART;
    const int NB_GT = (N_NODES + 127) / 128;
    const int NB_ND = (N_NODES + 3) / 4;

    // ---- CSR build (once; real edges only) ----
    zero_deg<<<NB_N, 256, 0, stream>>>(deg);
    hist_dst<<<NB_E8, 256, 0, stream>>>(ei, deg);
    scan1<<<NB_N, 256, 0, stream>>>(deg, rowptr, partial);
    scan2<<<1, 256, 0, stream>>>(partial, NB_N);
    scan3<<<NB_N, 256, 0, stream>>>(rowptr, partial, deg);
    scatter<<<NB_E8, 256, 0, stream>>>(ei, rowptr, deg, csr);

    // ---- layer 1 ----
    gemm_tile<F_IN><<<NB_GT, 256, 0, stream>>>(x, W1, bufH, a1s, a1d, alS, alD, N_NODES);
    node_agg<0><<<NB_ND, 256, 0, stream>>>(rowptr, csr, alS, alD, bufH, b1, bufB,
                                           nullptr, nullptr, nullptr);
    // ---- layer 2 ----
    gemm_tile<HID><<<NB_GT, 256, 0, stream>>>(bufB, W2, bufH, a2s, a2d, alS, alD, N_NODES);
    node_agg<0><<<NB_ND, 256, 0, stream>>>(rowptr, csr, alS, alD, bufH, b2, bufB,
                                           nullptr, nullptr, nullptr);
    // ---- layer 3 (fused FC) ----
    gemm_tile<HID><<<NB_GT, 256, 0, stream>>>(bufB, W3, bufH, a3s, a3d, alS, alD, N_NODES);
    node_agg<1><<<NB_ND, 256, 0, stream>>>(rowptr, csr, alS, alD, bufH, b3, nullptr,
                                           fcw, fcb, out);

    (void)in_sizes; (void)n_in; (void)out_size; (void)ws_size;
}

// Round 9
// 257.851 us; speedup vs baseline: 1.1404x; 1.1404x over previous
//
#include <hip/hip_runtime.h>
#include <math.h>

#define N_NODES 50000
#define E_EDGES 800000
#define F_IN 16
#define H_HEADS 8
#define HID 128
#define NEG_SLOPE 0.2f
#define N_PART 8
#define PART_SZ ((N_NODES + N_PART - 1) / N_PART)  // 6250

typedef __attribute__((ext_vector_type(8))) short short8v;   // 8 bf16 (4 VGPR)
typedef __attribute__((ext_vector_type(4))) float f32x4;

// f32 -> bf16 round-to-nearest-even
__device__ __forceinline__ unsigned short f2bf(float f) {
    unsigned u = __float_as_uint(f);
    return (unsigned short)((u + 0x7FFFu + ((u >> 16) & 1u)) >> 16);
}

// ========================= CSR build (real edges only; self-loops analytic) =========================

__global__ void zero_deg(int* __restrict__ deg) {
    int t = blockIdx.x * 256 + threadIdx.x;
    if (t < N_NODES) deg[t] = 0;
}

__global__ void hist_dst(const int* __restrict__ ei, int* __restrict__ deg) {
    int part = blockIdx.x & 7;
    int e = (blockIdx.x >> 3) * 256 + threadIdx.x;
    if (e >= E_EDGES) return;
    int d = ei[E_EDGES + e];
    if (d / PART_SZ == part) atomicAdd(&deg[d], 1);
}

__global__ void scan1(const int* __restrict__ deg, int* __restrict__ rowptr,
                      int* __restrict__ partial) {
    __shared__ int tmp[256];
    int tid = threadIdx.x;
    int t = blockIdx.x * 256 + tid;
    int v = (t < N_NODES) ? deg[t] : 0;
    tmp[tid] = v;
    __syncthreads();
    for (int off = 1; off < 256; off <<= 1) {
        int add = (tid >= off) ? tmp[tid - off] : 0;
        __syncthreads();
        tmp[tid] += add;
        __syncthreads();
    }
    if (t < N_NODES) rowptr[t] = tmp[tid] - v;
    if (tid == 255) partial[blockIdx.x] = tmp[255];
}

__global__ void scan2(int* __restrict__ partial, int nblk) {
    __shared__ int tmp[256];
    int tid = threadIdx.x;
    int v = (tid < nblk) ? partial[tid] : 0;
    tmp[tid] = v;
    __syncthreads();
    for (int off = 1; off < 256; off <<= 1) {
        int add = (tid >= off) ? tmp[tid - off] : 0;
        __syncthreads();
        tmp[tid] += add;
        __syncthreads();
    }
    if (tid < nblk) partial[tid] = tmp[tid] - v;
}

__global__ void scan3(int* __restrict__ rowptr, const int* __restrict__ partial,
                      int* __restrict__ deg) {
    int t = blockIdx.x * 256 + threadIdx.x;
    if (t < N_NODES) {
        rowptr[t] += partial[blockIdx.x];
        deg[t] = 0;
    }
    if (t == 0) rowptr[N_NODES] = E_EDGES;
}

__global__ void scatter(const int* __restrict__ ei, const int* __restrict__ rowptr,
                        int* __restrict__ cursor, int* __restrict__ csr) {
    int part = blockIdx.x & 7;
    int e = (blockIdx.x >> 3) * 256 + threadIdx.x;
    if (e >= E_EDGES) return;
    int d = ei[E_EDGES + e];
    if (d / PART_SZ != part) return;
    int s = ei[e];
    int pos = atomicAdd(&cursor[d], 1);
    csr[rowptr[d] + pos] = s;
}

// ========== layer-1 GEMM (K=16, fp32 tile, fused AL dots) ==========
template <int K>
__global__ __launch_bounds__(256) void gemm_tile(const float* __restrict__ A,
                                                 const float* __restrict__ W,
                                                 unsigned short* __restrict__ C,
                                                 const float* __restrict__ a_src,
                                                 const float* __restrict__ a_dst,
                                                 float* __restrict__ alS,
                                                 float* __restrict__ alD, int M) {
    constexpr int BK = (K < 32) ? K : 32;
    constexpr int BKQ = BK / 4;
    __shared__ float sA[BK][128];  // transposed: sA[k][row]
    __shared__ float sW[BK][128];
    int tid = threadIdx.x;
    int tx = tid & 15, ty = tid >> 4;
    int row0 = blockIdx.x * 128;
    float acc[8][8] = {};

    for (int kc = 0; kc < K; kc += BK) {
#pragma unroll
        for (int f = tid; f < 128 * BKQ; f += 256) {
            int r = f / BKQ, kq = f % BKQ;
            int gr = row0 + r;
            float4 v = (gr < M) ? *(const float4*)(A + (size_t)gr * K + kc + kq * 4)
                                : make_float4(0.f, 0.f, 0.f, 0.f);
            sA[kq * 4 + 0][r] = v.x;
            sA[kq * 4 + 1][r] = v.y;
            sA[kq * 4 + 2][r] = v.z;
            sA[kq * 4 + 3][r] = v.w;
        }
#pragma unroll
        for (int f = tid; f < BK * 32; f += 256) {
            int kr = f / 32, cq = f % 32;
            *(float4*)(&sW[kr][cq * 4]) =
                *(const float4*)(W + (size_t)(kc + kr) * 128 + cq * 4);
        }
        __syncthreads();
#pragma unroll
        for (int k = 0; k < BK; k++) {
            float4 a0 = *(const float4*)(&sA[k][ty * 8]);
            float4 a1 = *(const float4*)(&sA[k][ty * 8 + 4]);
            float4 w0 = *(const float4*)(&sW[k][tx * 4]);
            float4 w1 = *(const float4*)(&sW[k][64 + tx * 4]);
            float av[8] = {a0.x, a0.y, a0.z, a0.w, a1.x, a1.y, a1.z, a1.w};
            float wv[8] = {w0.x, w0.y, w0.z, w0.w, w1.x, w1.y, w1.z, w1.w};
#pragma unroll
            for (int i = 0; i < 8; i++)
#pragma unroll
                for (int j = 0; j < 8; j++) acc[i][j] += av[i] * wv[j];
        }
        __syncthreads();
    }

    int hd0 = tx >> 2, co = (tx & 3) * 4;
    float4 as0 = *(const float4*)(a_src + hd0 * 16 + co);
    float4 as1 = *(const float4*)(a_src + (4 + hd0) * 16 + co);
    float4 ad0 = *(const float4*)(a_dst + hd0 * 16 + co);
    float4 ad1 = *(const float4*)(a_dst + (4 + hd0) * 16 + co);

#pragma unroll
    for (int i = 0; i < 8; i++) {
        int gr = row0 + ty * 8 + i;
        if (gr >= M) break;
        float4 c0 = make_float4(acc[i][0], acc[i][1], acc[i][2], acc[i][3]);
        float4 c1 = make_float4(acc[i][4], acc[i][5], acc[i][6], acc[i][7]);
        ushort4 p0 = {f2bf(c0.x), f2bf(c0.y), f2bf(c0.z), f2bf(c0.w)};
        ushort4 p1 = {f2bf(c1.x), f2bf(c1.y), f2bf(c1.z), f2bf(c1.w)};
        *(ushort4*)(C + (size_t)gr * 128 + tx * 4) = p0;
        *(ushort4*)(C + (size_t)gr * 128 + 64 + tx * 4) = p1;
        float s1a = c0.x * as0.x + c0.y * as0.y + c0.z * as0.z + c0.w * as0.w;
        float s1b = c1.x * as1.x + c1.y * as1.y + c1.z * as1.z + c1.w * as1.w;
        float s2a = c0.x * ad0.x + c0.y * ad0.y + c0.z * ad0.z + c0.w * ad0.w;
        float s2b = c1.x * ad1.x + c1.y * ad1.y + c1.z * ad1.z + c1.w * ad1.w;
        s1a += __shfl_xor(s1a, 1); s1a += __shfl_xor(s1a, 2);
        s1b += __shfl_xor(s1b, 1); s1b += __shfl_xor(s1b, 2);
        s2a += __shfl_xor(s2a, 1); s2a += __shfl_xor(s2a, 2);
        s2b += __shfl_xor(s2b, 1); s2b += __shfl_xor(s2b, 2);
        if ((tx & 3) == 0) {
            alS[gr * 8 + hd0] = s1a;
            alS[gr * 8 + 4 + hd0] = s1b;
            alD[gr * 8 + hd0] = s2a;
            alD[gr * 8 + 4 + hd0] = s2b;
        }
    }
}

// ========== W transpose + bf16 convert (once per layer-2/3 weight) ==========
// Wt[col][k] = bf16(W[k][col]); 128x128
__global__ void prep_wt(const float* __restrict__ W, unsigned short* __restrict__ Wt) {
    int t = blockIdx.x * 256 + threadIdx.x;
    if (t >= HID * HID) return;
    int col = t >> 7, k = t & 127;
    Wt[t] = f2bf(W[k * HID + col]);
}

// ========== layers-2/3 GEMM: bf16 MFMA 16x16x32, BM=128, full K=128 staged ==========
// Fragment layouts (cdna4_isa §10 / m89): A row=lane&15, k=(lane>>4)*8+e;
// B col=lane&15, same k; C/D col=lane&15, row=(lane>>4)*4+reg.
// LDS XOR-swizzle byte^=((row&7)<<4) kills the stride-256B 16-way conflict (G4).
__global__ __launch_bounds__(256) void gemm_mfma(const unsigned short* __restrict__ Abf,
                                                 const unsigned short* __restrict__ Wt,
                                                 unsigned short* __restrict__ C, int M) {
    __shared__ unsigned short sA[HID * HID];  // 32 KiB, swizzled row-major [row][k]
    __shared__ unsigned short sW[HID * HID];  // 32 KiB, swizzled [col][k]
    char* sAb = (char*)sA;
    char* sWb = (char*)sW;
    int tid = threadIdx.x;
    int row0 = blockIdx.x * 128;

    // stage: 2048 chunks of 16B each for A and W
#pragma unroll
    for (int i = 0; i < 8; i++) {
        int f = tid + i * 256;
        int r = f >> 4, c = f & 15;
        int dst = r * 256 + ((c * 16) ^ ((r & 7) << 4));
        int gr = row0 + r;
        short8v va = {0, 0, 0, 0, 0, 0, 0, 0};
        if (gr < M) va = *(const short8v*)(Abf + (size_t)gr * HID + c * 8);
        *(short8v*)(sAb + dst) = va;
        *(short8v*)(sWb + dst) = *(const short8v*)(Wt + r * HID + c * 8);
    }
    __syncthreads();

    int lane = tid & 63;
    int wv = tid >> 6;  // wave 0..3 -> rows [wv*32, wv*32+32)
    int l15 = lane & 15, kg = lane >> 4;
    f32x4 acc[2][8];
#pragma unroll
    for (int a = 0; a < 2; a++)
#pragma unroll
        for (int j = 0; j < 8; j++) acc[a][j] = f32x4{0.f, 0.f, 0.f, 0.f};

    int rowA0 = wv * 32 + l15;
    int rowA1 = rowA0 + 16;
    int xr = (rowA0 & 7) << 4;  // same for rowA1 (+16 preserves &7)

#pragma unroll
    for (int kt = 0; kt < 4; kt++) {
        int kb = kt * 64 + kg * 16;
        short8v a0 = *(const short8v*)(sAb + rowA0 * 256 + (kb ^ xr));
        short8v a1 = *(const short8v*)(sAb + rowA1 * 256 + (kb ^ xr));
#pragma unroll
        for (int j = 0; j < 8; j++) {
            int colr = j * 16 + l15;
            short8v b = *(const short8v*)(sWb + colr * 256 + (kb ^ ((colr & 7) << 4)));
            acc[0][j] = __builtin_amdgcn_mfma_f32_16x16x32_bf16(a0, b, acc[0][j], 0, 0, 0);
            acc[1][j] = __builtin_amdgcn_mfma_f32_16x16x32_bf16(a1, b, acc[1][j], 0, 0, 0);
        }
    }

    // epilogue: C/D col=l15 (within tile), rows = tilebase + kg*4 + reg
#pragma unroll
    for (int a = 0; a < 2; a++) {
        int rbase = row0 + wv * 32 + a * 16 + kg * 4;
#pragma unroll
        for (int j = 0; j < 8; j++) {
            int col = j * 16 + l15;
#pragma unroll
            for (int reg = 0; reg < 4; reg++) {
                int gr = rbase + reg;
                if (gr < M) C[(size_t)gr * HID + col] = f2bf(acc[a][j][reg]);
            }
        }
    }
}

// ========== per-(node,head) attention logits from bf16 h (layers 2/3) ==========
__global__ void calc_al(const unsigned short* __restrict__ hbf,
                        const float* __restrict__ a_src, const float* __restrict__ a_dst,
                        float* __restrict__ alS, float* __restrict__ alD) {
    int t = blockIdx.x * 256 + threadIdx.x;
    if (t >= N_NODES * H_HEADS) return;
    int n = t >> 3, hd = t & 7;
    const unsigned short* hr = hbf + (size_t)n * HID + hd * 16;
    float s1 = 0.f, s2 = 0.f;
#pragma unroll
    for (int c = 0; c < 16; c += 2) {
        unsigned g = *(const unsigned*)(hr + c);
        float v0 = __uint_as_float(g << 16);
        float v1 = __uint_as_float(g & 0xFFFF0000u);
        s1 += v0 * a_src[hd * 16 + c] + v1 * a_src[hd * 16 + c + 1];
        s2 += v0 * a_dst[hd * 16 + c] + v1 * a_dst[hd * 16 + c + 1];
    }
    alS[t] = s1;
    alD[t] = s2;
}

// ============ per-node aggregation (memory-floor structure from R6/R7) ============
// MODE 0 writes bf16 h_out (next layer's MFMA input); MODE 1 fuses the final FC.
template <int MODE>
__global__ void node_agg(const int* __restrict__ rowptr, const int* __restrict__ csr,
                         const float* __restrict__ alS, const float* __restrict__ alD,
                         const unsigned short* __restrict__ hbf, const float* __restrict__ b,
                         unsigned short* __restrict__ h_out, const float* __restrict__ fcw,
                         const float* __restrict__ fcb, float* __restrict__ fco) {
    int node = blockIdx.x * 4 + (threadIdx.x >> 6);
    if (node >= N_NODES) return;
    int lane = threadIdx.x & 63;
    int row0 = __builtin_amdgcn_readfirstlane(rowptr[node]);
    int deg = __builtin_amdgcn_readfirstlane(rowptr[node + 1]) - row0;
    int h0 = lane >> 3;
    float ald = alD[node * 8 + h0];

    // self-loop term
    float es = alS[node * 8 + h0] + ald;
    es = es > 0.f ? es : NEG_SLOPE * es;
    float ps = __expf(es);
    unsigned gsl = ((const unsigned*)(hbf + (size_t)node * HID))[lane];
    float ssum = ps;
    float acc0 = ps * __uint_as_float(gsl << 16);
    float acc1 = ps * __uint_as_float(gsl & 0xFFFF0000u);

    int i = 0;
    for (; i + 8 <= deg; i += 8) {
        int su[8];
#pragma unroll
        for (int j = 0; j < 8; j++)
            su[j] = __builtin_amdgcn_readfirstlane(csr[row0 + i + j]);
        float aa[8];
        unsigned gg[8];
#pragma unroll
        for (int j = 0; j < 8; j++) {
            aa[j] = alS[su[j] * 8 + h0];
            gg[j] = ((const unsigned*)(hbf + (size_t)su[j] * HID))[lane];
        }
#pragma unroll
        for (int j = 0; j < 8; j++) {
            float e0 = aa[j] + ald;
            e0 = e0 > 0.f ? e0 : NEG_SLOPE * e0;
            float p = __expf(e0);
            ssum += p;
            acc0 += p * __uint_as_float(gg[j] << 16);
            acc1 += p * __uint_as_float(gg[j] & 0xFFFF0000u);
        }
    }
    for (; i < deg; i++) {
        int s0 = __builtin_amdgcn_readfirstlane(csr[row0 + i]);
        float a0 = alS[s0 * 8 + h0];
        unsigned g0 = ((const unsigned*)(hbf + (size_t)s0 * HID))[lane];
        float e0 = a0 + ald;
        e0 = e0 > 0.f ? e0 : NEG_SLOPE * e0;
        float p0 = __expf(e0);
        ssum += p0;
        acc0 += p0 * __uint_as_float(g0 << 16);
        acc1 += p0 * __uint_as_float(g0 & 0xFFFF0000u);
    }

    float2 bv = *(const float2*)(b + lane * 2);
    float inv = 1.f / ssum;
    float v0 = acc0 * inv + bv.x;
    float v1 = acc1 * inv + bv.y;
    v0 = v0 > 0.f ? v0 : (__expf(v0) - 1.f);
    v1 = v1 > 0.f ? v1 : (__expf(v1) - 1.f);
    if (MODE == 0) {
        unsigned pk = (unsigned)f2bf(v0) | ((unsigned)f2bf(v1) << 16);
        ((unsigned*)h_out)[(size_t)node * 64 + lane] = pk;
    } else {
        float2 fw = *(const float2*)(fcw + lane * 2);
        float r = v0 * fw.x + v1 * fw.y;
#pragma unroll
        for (int off = 32; off; off >>= 1) r += __shfl_down(r, off);
        if (lane == 0) fco[node] = r + fcb[0];
    }
}

// ========================= launch =========================

extern "C" void kernel_launch(void* const* d_in, const int* in_sizes, int n_in,
                              void* d_out, int out_size, void* d_ws, size_t ws_size,
                              hipStream_t stream) {
    const float* x   = (const float*)d_in[0];
    const int*   ei  = (const int*)d_in[1];
    const float* W1  = (const float*)d_in[2];
    const float* a1s = (const float*)d_in[3];
    const float* a1d = (const float*)d_in[4];
    const float* b1  = (const float*)d_in[5];
    const float* W2  = (const float*)d_in[6];
    const float* a2s = (const float*)d_in[7];
    const float* a2d = (const float*)d_in[8];
    const float* b2  = (const float*)d_in[9];
    const float* W3  = (const float*)d_in[10];
    const float* a3s = (const float*)d_in[11];
    const float* a3d = (const float*)d_in[12];
    const float* b3  = (const float*)d_in[13];
    const float* fcw = (const float*)d_in[14];
    const float* fcb = (const float*)d_in[15];
    float* out = (float*)d_out;

    char* ws = (char*)d_ws;
    size_t off = 0;
    unsigned short* bufH = (unsigned short*)(ws + off); off += (size_t)N_NODES * HID * 2;  // gemm out
    unsigned short* bufB = (unsigned short*)(ws + off); off += (size_t)N_NODES * HID * 2;  // agg out (bf16)
    unsigned short* Wt2  = (unsigned short*)(ws + off); off += (size_t)HID * HID * 2;
    unsigned short* Wt3  = (unsigned short*)(ws + off); off += (size_t)HID * HID * 2;
    float* alS  = (float*)(ws + off); off += (size_t)N_NODES * H_HEADS * 4;
    float* alD  = (float*)(ws + off); off += (size_t)N_NODES * H_HEADS * 4;
    int* deg    = (int*)(ws + off);   off += (size_t)N_NODES * 4;
    int* rowptr = (int*)(ws + off);   off += (size_t)(N_NODES + 1) * 4;
    int* partial= (int*)(ws + off);   off += 256 * 4;
    int* csr    = (int*)(ws + off);   off += (size_t)E_EDGES * 4;

    const int NB_N  = (N_NODES + 255) / 256;
    const int NB_E8 = ((E_EDGES + 255) / 256) * N_PART;
    const int NB_GT = (N_NODES + 127) / 128;
    const int NB_ND = (N_NODES + 3) / 4;
    const int NB_AL = (N_NODES * H_HEADS + 255) / 256;
    const int NB_WT = (HID * HID + 255) / 256;

    // ---- CSR build (once; real edges only) ----
    zero_deg<<<NB_N, 256, 0, stream>>>(deg);
    hist_dst<<<NB_E8, 256, 0, stream>>>(ei, deg);
    scan1<<<NB_N, 256, 0, stream>>>(deg, rowptr, partial);
    scan2<<<1, 256, 0, stream>>>(partial, NB_N);
    scan3<<<NB_N, 256, 0, stream>>>(rowptr, partial, deg);
    scatter<<<NB_E8, 256, 0, stream>>>(ei, rowptr, deg, csr);
    // ---- weight prep (independent of CSR; overlaps fine in-order) ----
    prep_wt<<<NB_WT, 256, 0, stream>>>(W2, Wt2);
    prep_wt<<<NB_WT, 256, 0, stream>>>(W3, Wt3);

    // ---- layer 1 (fp32 tile, fused al) ----
    gemm_tile<F_IN><<<NB_GT, 256, 0, stream>>>(x, W1, bufH, a1s, a1d, alS, alD, N_NODES);
    node_agg<0><<<NB_ND, 256, 0, stream>>>(rowptr, csr, alS, alD, bufH, b1, bufB,
                                           nullptr, nullptr, nullptr);
    // ---- layer 2 (bf16 MFMA) ----
    gemm_mfma<<<NB_GT, 256, 0, stream>>>(bufB, Wt2, bufH, N_NODES);
    calc_al<<<NB_AL, 256, 0, stream>>>(bufH, a2s, a2d, alS, alD);
    node_agg<0><<<NB_ND, 256, 0, stream>>>(rowptr, csr, alS, alD, bufH, b2, bufB,
                                           nullptr, nullptr, nullptr);
    // ---- layer 3 (bf16 MFMA, fused FC) ----
    gemm_mfma<<<NB_GT, 256, 0, stream>>>(bufB, Wt3, bufH, N_NODES);
    calc_al<<<NB_AL, 256, 0, stream>>>(bufH, a3s, a3d, alS, alD);
    node_agg<1><<<NB_ND, 256, 0, stream>>>(rowptr, csr, alS, alD, bufH, b3, nullptr,
                                           fcw, fcb, out);

    (void)in_sizes; (void)n_in; (void)out_size; (void)ws_size;
}

// Round 10
// 248.487 us; speedup vs baseline: 1.1833x; 1.0377x over previous
//
#include <hip/hip_runtime.h>
#include <math.h>

#define N_NODES 50000
#define E_EDGES 800000
#define F_IN 16
#define H_HEADS 8
#define HID 128
#define NEG_SLOPE 0.2f
#define N_PART 8
#define PART_SZ ((N_NODES + N_PART - 1) / N_PART)  // 6250

typedef __attribute__((ext_vector_type(8))) short short8v;   // 8 bf16 (4 VGPR)
typedef __attribute__((ext_vector_type(4))) float f32x4;

// f32 -> bf16 round-to-nearest-even
__device__ __forceinline__ unsigned short f2bf(float f) {
    unsigned u = __float_as_uint(f);
    return (unsigned short)((u + 0x7FFFu + ((u >> 16) & 1u)) >> 16);
}

// ========================= setup: zero deg + bf16-transpose W2/W3 =========================
__global__ void setup(int* __restrict__ deg, const float* __restrict__ W2,
                      unsigned short* __restrict__ Wt2, const float* __restrict__ W3,
                      unsigned short* __restrict__ Wt3) {
    int t = blockIdx.x * 256 + threadIdx.x;
    if (t < N_NODES) deg[t] = 0;
    if (t < HID * HID) {
        int col = t >> 7, k = t & 127;
        Wt2[t] = f2bf(W2[k * HID + col]);
        Wt3[t] = f2bf(W3[k * HID + col]);
    }
}

// ========================= CSR build (real edges only; self-loops analytic) =========================

__global__ void hist_dst(const int* __restrict__ ei, int* __restrict__ deg) {
    int part = blockIdx.x & 7;
    int e = (blockIdx.x >> 3) * 256 + threadIdx.x;
    if (e >= E_EDGES) return;
    int d = ei[E_EDGES + e];
    if (d / PART_SZ == part) atomicAdd(&deg[d], 1);
}

__global__ void scan1(const int* __restrict__ deg, int* __restrict__ rowptr,
                      int* __restrict__ partial) {
    __shared__ int tmp[256];
    int tid = threadIdx.x;
    int t = blockIdx.x * 256 + tid;
    int v = (t < N_NODES) ? deg[t] : 0;
    tmp[tid] = v;
    __syncthreads();
    for (int off = 1; off < 256; off <<= 1) {
        int add = (tid >= off) ? tmp[tid - off] : 0;
        __syncthreads();
        tmp[tid] += add;
        __syncthreads();
    }
    if (t < N_NODES) rowptr[t] = tmp[tid] - v;
    if (tid == 255) partial[blockIdx.x] = tmp[255];
}

__global__ void scan2(int* __restrict__ partial, int nblk) {
    __shared__ int tmp[256];
    int tid = threadIdx.x;
    int v = (tid < nblk) ? partial[tid] : 0;
    tmp[tid] = v;
    __syncthreads();
    for (int off = 1; off < 256; off <<= 1) {
        int add = (tid >= off) ? tmp[tid - off] : 0;
        __syncthreads();
        tmp[tid] += add;
        __syncthreads();
    }
    if (tid < nblk) partial[tid] = tmp[tid] - v;
}

__global__ void scan3(int* __restrict__ rowptr, const int* __restrict__ partial,
                      int* __restrict__ deg) {
    int t = blockIdx.x * 256 + threadIdx.x;
    if (t < N_NODES) {
        rowptr[t] += partial[blockIdx.x];
        deg[t] = 0;
    }
    if (t == 0) rowptr[N_NODES] = E_EDGES;
}

__global__ void scatter(const int* __restrict__ ei, const int* __restrict__ rowptr,
                        int* __restrict__ cursor, int* __restrict__ csr) {
    int part = blockIdx.x & 7;
    int e = (blockIdx.x >> 3) * 256 + threadIdx.x;
    if (e >= E_EDGES) return;
    int d = ei[E_EDGES + e];
    if (d / PART_SZ != part) return;
    int s = ei[e];
    int pos = atomicAdd(&cursor[d], 1);
    csr[rowptr[d] + pos] = s;
}

// ========== layer-1 GEMM (K=16, fp32 tile, fused AL dots) ==========
template <int K>
__global__ __launch_bounds__(256) void gemm_tile(const float* __restrict__ A,
                                                 const float* __restrict__ W,
                                                 unsigned short* __restrict__ C,
                                                 const float* __restrict__ a_src,
                                                 const float* __restrict__ a_dst,
                                                 float* __restrict__ alS,
                                                 float* __restrict__ alD, int M) {
    constexpr int BK = (K < 32) ? K : 32;
    constexpr int BKQ = BK / 4;
    __shared__ float sA[BK][128];  // transposed: sA[k][row]
    __shared__ float sW[BK][128];
    int tid = threadIdx.x;
    int tx = tid & 15, ty = tid >> 4;
    int row0 = blockIdx.x * 128;
    float acc[8][8] = {};

    for (int kc = 0; kc < K; kc += BK) {
#pragma unroll
        for (int f = tid; f < 128 * BKQ; f += 256) {
            int r = f / BKQ, kq = f % BKQ;
            int gr = row0 + r;
            float4 v = (gr < M) ? *(const float4*)(A + (size_t)gr * K + kc + kq * 4)
                                : make_float4(0.f, 0.f, 0.f, 0.f);
            sA[kq * 4 + 0][r] = v.x;
            sA[kq * 4 + 1][r] = v.y;
            sA[kq * 4 + 2][r] = v.z;
            sA[kq * 4 + 3][r] = v.w;
        }
#pragma unroll
        for (int f = tid; f < BK * 32; f += 256) {
            int kr = f / 32, cq = f % 32;
            *(float4*)(&sW[kr][cq * 4]) =
                *(const float4*)(W + (size_t)(kc + kr) * 128 + cq * 4);
        }
        __syncthreads();
#pragma unroll
        for (int k = 0; k < BK; k++) {
            float4 a0 = *(const float4*)(&sA[k][ty * 8]);
            float4 a1 = *(const float4*)(&sA[k][ty * 8 + 4]);
            float4 w0 = *(const float4*)(&sW[k][tx * 4]);
            float4 w1 = *(const float4*)(&sW[k][64 + tx * 4]);
            float av[8] = {a0.x, a0.y, a0.z, a0.w, a1.x, a1.y, a1.z, a1.w};
            float wv[8] = {w0.x, w0.y, w0.z, w0.w, w1.x, w1.y, w1.z, w1.w};
#pragma unroll
            for (int i = 0; i < 8; i++)
#pragma unroll
                for (int j = 0; j < 8; j++) acc[i][j] += av[i] * wv[j];
        }
        __syncthreads();
    }

    int hd0 = tx >> 2, co = (tx & 3) * 4;
    float4 as0 = *(const float4*)(a_src + hd0 * 16 + co);
    float4 as1 = *(const float4*)(a_src + (4 + hd0) * 16 + co);
    float4 ad0 = *(const float4*)(a_dst + hd0 * 16 + co);
    float4 ad1 = *(const float4*)(a_dst + (4 + hd0) * 16 + co);

#pragma unroll
    for (int i = 0; i < 8; i++) {
        int gr = row0 + ty * 8 + i;
        if (gr >= M) break;
        float4 c0 = make_float4(acc[i][0], acc[i][1], acc[i][2], acc[i][3]);
        float4 c1 = make_float4(acc[i][4], acc[i][5], acc[i][6], acc[i][7]);
        ushort4 p0 = {f2bf(c0.x), f2bf(c0.y), f2bf(c0.z), f2bf(c0.w)};
        ushort4 p1 = {f2bf(c1.x), f2bf(c1.y), f2bf(c1.z), f2bf(c1.w)};
        *(ushort4*)(C + (size_t)gr * 128 + tx * 4) = p0;
        *(ushort4*)(C + (size_t)gr * 128 + 64 + tx * 4) = p1;
        float s1a = c0.x * as0.x + c0.y * as0.y + c0.z * as0.z + c0.w * as0.w;
        float s1b = c1.x * as1.x + c1.y * as1.y + c1.z * as1.z + c1.w * as1.w;
        float s2a = c0.x * ad0.x + c0.y * ad0.y + c0.z * ad0.z + c0.w * ad0.w;
        float s2b = c1.x * ad1.x + c1.y * ad1.y + c1.z * ad1.z + c1.w * ad1.w;
        s1a += __shfl_xor(s1a, 1); s1a += __shfl_xor(s1a, 2);
        s1b += __shfl_xor(s1b, 1); s1b += __shfl_xor(s1b, 2);
        s2a += __shfl_xor(s2a, 1); s2a += __shfl_xor(s2a, 2);
        s2b += __shfl_xor(s2b, 1); s2b += __shfl_xor(s2b, 2);
        if ((tx & 3) == 0) {
            alS[gr * 8 + hd0] = s1a;
            alS[gr * 8 + 4 + hd0] = s1b;
            alD[gr * 8 + hd0] = s2a;
            alD[gr * 8 + 4 + hd0] = s2b;
        }
    }
}

// ========== layers-2/3 GEMM: bf16 MFMA 16x16x32, BM=128, full K=128 staged ==========
__global__ __launch_bounds__(256) void gemm_mfma(const unsigned short* __restrict__ Abf,
                                                 const unsigned short* __restrict__ Wt,
                                                 unsigned short* __restrict__ C, int M) {
    __shared__ unsigned short sA[HID * HID];  // 32 KiB, swizzled row-major [row][k]
    __shared__ unsigned short sW[HID * HID];  // 32 KiB, swizzled [col][k]
    char* sAb = (char*)sA;
    char* sWb = (char*)sW;
    int tid = threadIdx.x;
    int row0 = blockIdx.x * 128;

#pragma unroll
    for (int i = 0; i < 8; i++) {
        int f = tid + i * 256;
        int r = f >> 4, c = f & 15;
        int dst = r * 256 + ((c * 16) ^ ((r & 7) << 4));
        int gr = row0 + r;
        short8v va = {0, 0, 0, 0, 0, 0, 0, 0};
        if (gr < M) va = *(const short8v*)(Abf + (size_t)gr * HID + c * 8);
        *(short8v*)(sAb + dst) = va;
        *(short8v*)(sWb + dst) = *(const short8v*)(Wt + r * HID + c * 8);
    }
    __syncthreads();

    int lane = tid & 63;
    int wv = tid >> 6;
    int l15 = lane & 15, kg = lane >> 4;
    f32x4 acc[2][8];
#pragma unroll
    for (int a = 0; a < 2; a++)
#pragma unroll
        for (int j = 0; j < 8; j++) acc[a][j] = f32x4{0.f, 0.f, 0.f, 0.f};

    int rowA0 = wv * 32 + l15;
    int rowA1 = rowA0 + 16;
    int xr = (rowA0 & 7) << 4;

#pragma unroll
    for (int kt = 0; kt < 4; kt++) {
        int kb = kt * 64 + kg * 16;
        short8v a0 = *(const short8v*)(sAb + rowA0 * 256 + (kb ^ xr));
        short8v a1 = *(const short8v*)(sAb + rowA1 * 256 + (kb ^ xr));
#pragma unroll
        for (int j = 0; j < 8; j++) {
            int colr = j * 16 + l15;
            short8v b = *(const short8v*)(sWb + colr * 256 + (kb ^ ((colr & 7) << 4)));
            acc[0][j] = __builtin_amdgcn_mfma_f32_16x16x32_bf16(a0, b, acc[0][j], 0, 0, 0);
            acc[1][j] = __builtin_amdgcn_mfma_f32_16x16x32_bf16(a1, b, acc[1][j], 0, 0, 0);
        }
    }

#pragma unroll
    for (int a = 0; a < 2; a++) {
        int rbase = row0 + wv * 32 + a * 16 + kg * 4;
#pragma unroll
        for (int j = 0; j < 8; j++) {
            int col = j * 16 + l15;
#pragma unroll
            for (int reg = 0; reg < 4; reg++) {
                int gr = rbase + reg;
                if (gr < M) C[(size_t)gr * HID + col] = f2bf(acc[a][j][reg]);
            }
        }
    }
}

// ========== per-(node,head) attention logits from bf16 h (layers 2/3) ==========
__global__ void calc_al(const unsigned short* __restrict__ hbf,
                        const float* __restrict__ a_src, const float* __restrict__ a_dst,
                        float* __restrict__ alS, float* __restrict__ alD) {
    int t = blockIdx.x * 256 + threadIdx.x;
    if (t >= N_NODES * H_HEADS) return;
    int n = t >> 3, hd = t & 7;
    const unsigned short* hr = hbf + (size_t)n * HID + hd * 16;
    float s1 = 0.f, s2 = 0.f;
#pragma unroll
    for (int c = 0; c < 16; c += 2) {
        unsigned g = *(const unsigned*)(hr + c);
        float v0 = __uint_as_float(g << 16);
        float v1 = __uint_as_float(g & 0xFFFF0000u);
        s1 += v0 * a_src[hd * 16 + c] + v1 * a_src[hd * 16 + c + 1];
        s2 += v0 * a_dst[hd * 16 + c] + v1 * a_dst[hd * 16 + c + 1];
    }
    alS[t] = s1;
    alD[t] = s2;
}

// ============ per-node aggregation: 16/4/1 unroll (MLP-depth probe) ============
template <int MODE>
__global__ void node_agg(const int* __restrict__ rowptr, const int* __restrict__ csr,
                         const float* __restrict__ alS, const float* __restrict__ alD,
                         const unsigned short* __restrict__ hbf, const float* __restrict__ b,
                         unsigned short* __restrict__ h_out, const float* __restrict__ fcw,
                         const float* __restrict__ fcb, float* __restrict__ fco) {
    int node = blockIdx.x * 4 + (threadIdx.x >> 6);
    if (node >= N_NODES) return;
    int lane = threadIdx.x & 63;
    int row0 = __builtin_amdgcn_readfirstlane(rowptr[node]);
    int deg = __builtin_amdgcn_readfirstlane(rowptr[node + 1]) - row0;
    int h0 = lane >> 3;
    float ald = alD[node * 8 + h0];

    // self-loop term
    float es = alS[node * 8 + h0] + ald;
    es = es > 0.f ? es : NEG_SLOPE * es;
    float ps = __expf(es);
    unsigned gsl = ((const unsigned*)(hbf + (size_t)node * HID))[lane];
    float ssum = ps;
    float acc0 = ps * __uint_as_float(gsl << 16);
    float acc1 = ps * __uint_as_float(gsl & 0xFFFF0000u);

    int i = 0;
    for (; i + 16 <= deg; i += 16) {
        int su[16];
#pragma unroll
        for (int j = 0; j < 16; j++)
            su[j] = __builtin_amdgcn_readfirstlane(csr[row0 + i + j]);
        float aa[16];
        unsigned gg[16];
#pragma unroll
        for (int j = 0; j < 16; j++) {
            aa[j] = alS[su[j] * 8 + h0];
            gg[j] = ((const unsigned*)(hbf + (size_t)su[j] * HID))[lane];
        }
#pragma unroll
        for (int j = 0; j < 16; j++) {
            float e0 = aa[j] + ald;
            e0 = e0 > 0.f ? e0 : NEG_SLOPE * e0;
            float p = __expf(e0);
            ssum += p;
            acc0 += p * __uint_as_float(gg[j] << 16);
            acc1 += p * __uint_as_float(gg[j] & 0xFFFF0000u);
        }
    }
    for (; i + 4 <= deg; i += 4) {
        int su[4];
#pragma unroll
        for (int j = 0; j < 4; j++)
            su[j] = __builtin_amdgcn_readfirstlane(csr[row0 + i + j]);
        float aa[4];
        unsigned gg[4];
#pragma unroll
        for (int j = 0; j < 4; j++) {
            aa[j] = alS[su[j] * 8 + h0];
            gg[j] = ((const unsigned*)(hbf + (size_t)su[j] * HID))[lane];
        }
#pragma unroll
        for (int j = 0; j < 4; j++) {
            float e0 = aa[j] + ald;
            e0 = e0 > 0.f ? e0 : NEG_SLOPE * e0;
            float p = __expf(e0);
            ssum += p;
            acc0 += p * __uint_as_float(gg[j] << 16);
            acc1 += p * __uint_as_float(gg[j] & 0xFFFF0000u);
        }
    }
    for (; i < deg; i++) {
        int s0 = __builtin_amdgcn_readfirstlane(csr[row0 + i]);
        float a0 = alS[s0 * 8 + h0];
        unsigned g0 = ((const unsigned*)(hbf + (size_t)s0 * HID))[lane];
        float e0 = a0 + ald;
        e0 = e0 > 0.f ? e0 : NEG_SLOPE * e0;
        float p0 = __expf(e0);
        ssum += p0;
        acc0 += p0 * __uint_as_float(g0 << 16);
        acc1 += p0 * __uint_as_float(g0 & 0xFFFF0000u);
    }

    float2 bv = *(const float2*)(b + lane * 2);
    float inv = 1.f / ssum;
    float v0 = acc0 * inv + bv.x;
    float v1 = acc1 * inv + bv.y;
    v0 = v0 > 0.f ? v0 : (__expf(v0) - 1.f);
    v1 = v1 > 0.f ? v1 : (__expf(v1) - 1.f);
    if (MODE == 0) {
        unsigned pk = (unsigned)f2bf(v0) | ((unsigned)f2bf(v1) << 16);
        ((unsigned*)h_out)[(size_t)node * 64 + lane] = pk;
    } else {
        float2 fw = *(const float2*)(fcw + lane * 2);
        float r = v0 * fw.x + v1 * fw.y;
#pragma unroll
        for (int off = 32; off; off >>= 1) r += __shfl_down(r, off);
        if (lane == 0) fco[node] = r + fcb[0];
    }
}

// ========================= launch =========================

extern "C" void kernel_launch(void* const* d_in, const int* in_sizes, int n_in,
                              void* d_out, int out_size, void* d_ws, size_t ws_size,
                              hipStream_t stream) {
    const float* x   = (const float*)d_in[0];
    const int*   ei  = (const int*)d_in[1];
    const float* W1  = (const float*)d_in[2];
    const float* a1s = (const float*)d_in[3];
    const float* a1d = (const float*)d_in[4];
    const float* b1  = (const float*)d_in[5];
    const float* W2  = (const float*)d_in[6];
    const float* a2s = (const float*)d_in[7];
    const float* a2d = (const float*)d_in[8];
    const float* b2  = (const float*)d_in[9];
    const float* W3  = (const float*)d_in[10];
    const float* a3s = (const float*)d_in[11];
    const float* a3d = (const float*)d_in[12];
    const float* b3  = (const float*)d_in[13];
    const float* fcw = (const float*)d_in[14];
    const float* fcb = (const float*)d_in[15];
    float* out = (float*)d_out;

    char* ws = (char*)d_ws;
    size_t off = 0;
    unsigned short* bufH = (unsigned short*)(ws + off); off += (size_t)N_NODES * HID * 2;
    unsigned short* bufB = (unsigned short*)(ws + off); off += (size_t)N_NODES * HID * 2;
    unsigned short* Wt2  = (unsigned short*)(ws + off); off += (size_t)HID * HID * 2;
    unsigned short* Wt3  = (unsigned short*)(ws + off); off += (size_t)HID * HID * 2;
    float* alS  = (float*)(ws + off); off += (size_t)N_NODES * H_HEADS * 4;
    float* alD  = (float*)(ws + off); off += (size_t)N_NODES * H_HEADS * 4;
    int* deg    = (int*)(ws + off);   off += (size_t)N_NODES * 4;
    int* rowptr = (int*)(ws + off);   off += (size_t)(N_NODES + 1) * 4;
    int* partial= (int*)(ws + off);   off += 256 * 4;
    int* csr    = (int*)(ws + off);   off += (size_t)E_EDGES * 4;

    const int NB_N  = (N_NODES + 255) / 256;
    const int NB_E8 = ((E_EDGES + 255) / 256) * N_PART;
    const int NB_GT = (N_NODES + 127) / 128;
    const int NB_ND = (N_NODES + 3) / 4;
    const int NB_AL = (N_NODES * H_HEADS + 255) / 256;

    // ---- setup + CSR build (once; real edges only) ----
    setup<<<NB_N, 256, 0, stream>>>(deg, W2, Wt2, W3, Wt3);
    hist_dst<<<NB_E8, 256, 0, stream>>>(ei, deg);
    scan1<<<NB_N, 256, 0, stream>>>(deg, rowptr, partial);
    scan2<<<1, 256, 0, stream>>>(partial, NB_N);
    scan3<<<NB_N, 256, 0, stream>>>(rowptr, partial, deg);
    scatter<<<NB_E8, 256, 0, stream>>>(ei, rowptr, deg, csr);

    // ---- layer 1 (fp32 tile, fused al) ----
    gemm_tile<F_IN><<<NB_GT, 256, 0, stream>>>(x, W1, bufH, a1s, a1d, alS, alD, N_NODES);
    node_agg<0><<<NB_ND, 256, 0, stream>>>(rowptr, csr, alS, alD, bufH, b1, bufB,
                                           nullptr, nullptr, nullptr);
    // ---- layer 2 (bf16 MFMA) ----
    gemm_mfma<<<NB_GT, 256, 0, stream>>>(bufB, Wt2, bufH, N_NODES);
    calc_al<<<NB_AL, 256, 0, stream>>>(bufH, a2s, a2d, alS, alD);
    node_agg<0><<<NB_ND, 256, 0, stream>>>(rowptr, csr, alS, alD, bufH, b2, bufB,
                                           nullptr, nullptr, nullptr);
    // ---- layer 3 (bf16 MFMA, fused FC) ----
    gemm_mfma<<<NB_GT, 256, 0, stream>>>(bufB, Wt3, bufH, N_NODES);
    calc_al<<<NB_AL, 256, 0, stream>>>(bufH, a3s, a3d, alS, alD);
    node_agg<1><<<NB_ND, 256, 0, stream>>>(rowptr, csr, alS, alD, bufH, b3, nullptr,
                                           fcw, fcb, out);

    (void)in_sizes; (void)n_in; (void)out_size; (void)ws_size;
}